// Round 8
// baseline (315.275 us; speedup 1.0000x reference)
//
#include <hip/hip_runtime.h>

// ---------------------------------------------------------------------------
// EdgeFeatureNet: B=1, N=512, NODE_DIM=256, HID=128, EDGE_DIM=128, bins=22
//
// h1_pre[i,j] = A[i] + Bv[j] + R[i-j+511] + W1row[384+binD] + W1row[406+binS]
// h2 = relu(h1@W2+b2), h3 = h2@W3+b3, LayerNorm, * edge_mask.
//
// Round-8 = ROUND-5 VERIFIED BASE (grid 1024, half-row blocks, passed at
// 249.9 us total / 100 us edge_main) + ONE change: A-fragment build is
// double-buffered across the two mt tiles (tile 1's gather loads issue
// before tile 0's compute). Round-6's full-row/grid-512 restructure is
// DROPPED: two consecutive container failures on that source vs a clean
// pass on this one — minimal-diff disambiguation.
// ---------------------------------------------------------------------------

using bf16x8 = __attribute__((ext_vector_type(8))) short;
using f32x4  = __attribute__((ext_vector_type(4))) float;

__device__ __forceinline__ unsigned short f2bf(float f) {
    unsigned int u;
    __builtin_memcpy(&u, &f, 4);
    unsigned int r = (u + 0x7fffu + ((u >> 16) & 1u)) >> 16;  // RNE
    return (unsigned short)r;
}

__device__ __forceinline__ unsigned int cvt_pk_bf16(float lo, float hi) {
    unsigned int r;
    asm("v_cvt_pk_bf16_f32 %0, %1, %2" : "=v"(r) : "v"(lo), "v"(hi));
    return r;
}

// ---------------------------------------------------------------------------
// pre_fast: 512 blocks x 512 threads (verified round 5, unchanged).
//   block i: A[i], Bv[i]; Rm rows {2i, 2i+1}; 64-elem W2b/W3b slice.
// ---------------------------------------------------------------------------
__global__ __launch_bounds__(512) void pre_fast(
    const float* __restrict__ nf,
    const float* __restrict__ flow,
    const float* __restrict__ Wn2e,
    const float* __restrict__ bn2e,
    const float* __restrict__ Wrp,
    const float* __restrict__ brp,
    const float* __restrict__ W1,
    const float* __restrict__ b1,
    const float* __restrict__ W2,
    const float* __restrict__ W3,
    float* __restrict__ Aw, float* __restrict__ Bv,
    float* __restrict__ Rm,
    short* __restrict__ W2b, short* __restrict__ W3b)
{
    __shared__ float nfs[256];
    __shared__ float n2s[128];
    __shared__ float red[512];
    __shared__ float emb[128];
    __shared__ float rp[128];

    const int bid = blockIdx.x;
    const int tid = threadIdx.x;
    const int i = bid;
    const int m = tid & 127, ks = tid >> 7;

    // (c) W2/W3 -> bf16 fragment layout, 64 values per block (independent)
    if (tid < 64) {
        const int idx = bid * 64 + tid;            // 0..32767
        const int v   = idx & 16383;
        const int k   = v >> 7, n = v & 127;
        const int dst = ((k >> 3) * 128 + n) * 8 + (k & 7);
        if (idx < 16384) W2b[dst] = (short)f2bf(W2[v]);
        else             W3b[dst] = (short)f2bf(W3[v]);
    }

    // (a) n2e[i] = nf[i] @ Wn2e + bn2e   (k = 0..255, 4 slices of 64)
    if (tid < 256) nfs[tid] = nf[i * 256 + tid];
    __syncthreads();
    {
        float p0 = 0.f, p1 = 0.f;
        #pragma unroll 8
        for (int k = ks * 64; k < ks * 64 + 64; k += 2) {
            p0 += nfs[k]     * Wn2e[k * 128 + m];
            p1 += nfs[k + 1] * Wn2e[(k + 1) * 128 + m];
        }
        red[tid] = p0 + p1;
    }
    __syncthreads();
    if (tid < 128)
        n2s[tid] = bn2e[tid] +
                   ((red[tid] + red[tid + 128]) + (red[tid + 256] + red[tid + 384]));
    __syncthreads();

    // A[i] = n2e@W1[0:128] + b1 + flow*W1[428];  Bv[i] = n2e@W1[128:256] + flow*W1[429]
    {
        float pa = 0.f, pb = 0.f;
        #pragma unroll 8
        for (int k = ks * 32; k < ks * 32 + 32; k++) {
            const float s = n2s[k];
            pa += s * W1[k * 128 + m];
            pb += s * W1[(128 + k) * 128 + m];
        }
        red[tid] = pa;
        __syncthreads();
        float pA = 0.f;
        if (tid < 128)
            pA = (red[tid] + red[tid + 128]) + (red[tid + 256] + red[tid + 384]);
        __syncthreads();
        red[tid] = pb;
        __syncthreads();
        if (tid < 128) {
            const float fl = flow[i];
            Aw[i * 128 + tid] = pA + b1[tid] + fl * W1[428 * 128 + tid];
            Bv[i * 128 + tid] =
                (red[tid] + red[tid + 128]) + (red[tid + 256] + red[tid + 384]) +
                fl * W1[429 * 128 + tid];
        }
    }
    __syncthreads();

    // (b) two Rm rows: dix = 2*bid, 2*bid+1 (valid 0..1022)
    for (int rr = 0; rr < 2; rr++) {
        const int dix = bid * 2 + rr;
        if (dix > 1022) break;                      // block-uniform
        const float d = (float)(dix - 511);
        if (tid < 128) {
            const int K = tid & 63;
            const float denom = powf(2056.0f, (float)K * (1.0f / 64.0f));
            const float ang = d * 3.14159265358979323846f / denom;
            emb[tid] = (tid < 64) ? sinf(ang) : cosf(ang);
        }
        __syncthreads();
        float p = 0.f;
        #pragma unroll 8
        for (int k = ks * 32; k < ks * 32 + 32; k++) p += emb[k] * Wrp[k * 128 + m];
        red[tid] = p;
        __syncthreads();
        if (tid < 128)
            rp[tid] = brp[tid] +
                      ((red[tid] + red[tid + 128]) + (red[tid + 256] + red[tid + 384]));
        __syncthreads();
        p = 0.f;
        #pragma unroll 8
        for (int k = ks * 32; k < ks * 32 + 32; k++) p += rp[k] * W1[(256 + k) * 128 + m];
        red[tid] = p;
        __syncthreads();
        if (tid < 128)
            Rm[dix * 128 + tid] =
                (red[tid] + red[tid + 128]) + (red[tid + 256] + red[tid + 384]);
        __syncthreads();
    }
}

// ---------------------------------------------------------------------------
// Main fused kernel: grid=1024 (i = bid>>1, j0 = (bid&1)*256), block=512.
// LDS ~66.5 KB -> 2 blocks/CU. One barrier. (Round-5 verified structure;
// only change: af double-buffer across the two mt tiles.)
// ---------------------------------------------------------------------------
__global__ __launch_bounds__(512, 4) void edge_main(
    const float* __restrict__ trans,
    const float* __restrict__ sctrans,
    const float* __restrict__ emask,
    const float* __restrict__ W1,
    const short* __restrict__ W2b,
    const float* __restrict__ b2,
    const short* __restrict__ W3b,
    const float* __restrict__ b3,
    const float* __restrict__ lng,
    const float* __restrict__ lnb,
    const float* __restrict__ A,
    const float* __restrict__ Bv,
    const float* __restrict__ Rm,
    float* __restrict__ out)
{
    __shared__ __align__(16) short W2L[16384];          // 32 KB, frag layout
    __shared__ __align__(16) short W3L[16384];          // 32 KB, frag layout
    __shared__ __align__(16) float As[128];
    __shared__ int binsD[256];
    __shared__ int binsS[256];

    const int tid = threadIdx.x;
    const int i  = blockIdx.x >> 1;
    const int j0 = (blockIdx.x & 1) << 8;

    // ---- async-stage weights into LDS: pure linear copy, 16 B/lane.
    for (int r = 0; r < 4; r++) {
        const int off = (r * 512 + tid) * 16;           // byte offset
        __builtin_amdgcn_global_load_lds(
            (const __attribute__((address_space(1))) void*)((const char*)W2b + off),
            (__attribute__((address_space(3))) void*)((char*)W2L + off), 16, 0, 0);
        __builtin_amdgcn_global_load_lds(
            (const __attribute__((address_space(1))) void*)((const char*)W3b + off),
            (__attribute__((address_space(3))) void*)((char*)W3L + off), 16, 0, 0);
    }

    if (tid < 128) As[tid] = A[i * 128 + tid];

    // ---- per-pair distogram bins (threads 0..255: trans, 256..511: sc_trans)
    {
        const int p = tid & 255;
        const float* P = (tid < 256) ? trans : sctrans;
        const int j = j0 + p;
        const float dx = __fsub_rn(P[i * 3 + 0], P[j * 3 + 0]);
        const float dy = __fsub_rn(P[i * 3 + 1], P[j * 3 + 1]);
        const float dz = __fsub_rn(P[i * 3 + 2], P[j * 3 + 2]);
        const float d2 = __fadd_rn(__fadd_rn(__fmul_rn(dx, dx), __fmul_rn(dy, dy)),
                                   __fmul_rn(dz, dz));
        const double dd = (double)sqrtf(d2);
        const double step = (20.0 - 0.001) / 21.0;
        int bin = -1;
        for (int b = 0; b < 22; b++) {
            const double lo = (b == 21) ? 20.0 : __dadd_rn(0.001, __dmul_rn((double)b, step));
            const double up = (b == 20) ? 20.0 :
                              ((b == 21) ? 1e8 : __dadd_rn(0.001, __dmul_rn((double)(b + 1), step)));
            if (dd > lo && dd < up) bin = b;
        }
        if (tid < 256) binsD[p] = bin; else binsS[p] = bin;
    }
    __syncthreads();   // only barrier: weights staged + bins + As

    const int w = tid >> 6;       // wave id: owns pairs [32w, 32w+32)
    const int l = tid & 63;
    const int q = l >> 4;         // quad within wave
    const int ln16 = l & 15;

    const f32x4 vzero = {0.0f, 0.0f, 0.0f, 0.0f};
    // bpermute source-lane addresses for the L2->L3 q-group permutation
    const int laA = (((q & 1) * 2) * 16 + ln16) * 4;    // source quad (q&1)*2
    const int laB = laA + 64;                            // source quad (q&1)*2+1
    const bool selHi = (q >> 1) != 0;

    // ---- h1 A-fragment builder (h1 row p = 32w + mt*16 + ln16)
    auto build_af = [&](int mt, bf16x8* dst) {
        const int p = 32 * w + mt * 16 + ln16;
        const int j = j0 + p;
        const int didx = i - j + 511;
        const int bD = binsD[p], bS = binsS[p];
        const float sD = bD >= 0 ? 1.0f : 0.0f;
        const float sS = bS >= 0 ? 1.0f : 0.0f;
        const int rD = 384 + (bD >= 0 ? bD : 0);
        const int rS = 406 + (bS >= 0 ? bS : 0);
        const float* __restrict__ BvR = &Bv[j * 128];
        const float* __restrict__ RmR = &Rm[didx * 128];
        const float* __restrict__ WdR = &W1[rD * 128];
        const float* __restrict__ WsR = &W1[rS * 128];
        #pragma unroll
        for (int kb = 0; kb < 4; kb++) {
            const int f0 = kb * 32 + q * 8;
            const f32x4 bv0 = *(const f32x4*)&BvR[f0];
            const f32x4 bv1 = *(const f32x4*)&BvR[f0 + 4];
            const f32x4 r0  = *(const f32x4*)&RmR[f0];
            const f32x4 r1  = *(const f32x4*)&RmR[f0 + 4];
            const f32x4 a0  = *(const f32x4*)&As[f0];
            const f32x4 a1  = *(const f32x4*)&As[f0 + 4];
            const f32x4 w0  = *(const f32x4*)&WdR[f0];
            const f32x4 w1  = *(const f32x4*)&WdR[f0 + 4];
            const f32x4 s0  = *(const f32x4*)&WsR[f0];
            const f32x4 s1  = *(const f32x4*)&WsR[f0 + 4];
            float h[8];
            #pragma unroll
            for (int e = 0; e < 4; e++) {
                h[e]     = fmaxf(a0[e] + bv0[e] + r0[e] + sD * w0[e] + sS * s0[e], 0.0f);
                h[e + 4] = fmaxf(a1[e] + bv1[e] + r1[e] + sD * w1[e] + sS * s1[e], 0.0f);
            }
            union { unsigned int u[4]; bf16x8 v; } cv;
            cv.u[0] = cvt_pk_bf16(h[0], h[1]);
            cv.u[1] = cvt_pk_bf16(h[2], h[3]);
            cv.u[2] = cvt_pk_bf16(h[4], h[5]);
            cv.u[3] = cvt_pk_bf16(h[6], h[7]);
            dst[kb] = cv.v;
        }
    };

    bf16x8 afA[4], afB[4];
    build_af(0, afA);

    for (int mt = 0; mt < 2; mt++) {
        // issue next tile's gather loads early: latency hides under compute
        if (mt < 1) build_af(1, afB);

        const int p = 32 * w + mt * 16 + ln16;          // local pair (row r)
        const int j = j0 + p;

        // ---- layer 2 TRANSPOSED: lane holds h2T[n = nt*16+q*4+rg][r = ln16]
        unsigned int P[8][2];
        #pragma unroll
        for (int nt = 0; nt < 8; nt++) {
            f32x4 acc2 = vzero;
            #pragma unroll
            for (int kb = 0; kb < 4; kb++) {
                const bf16x8 wf = *(const bf16x8*)&W2L[((kb * 4 + q) * 128 + nt * 16 + ln16) * 8];
                acc2 = __builtin_amdgcn_mfma_f32_16x16x32_bf16(wf, afA[kb], acc2, 0, 0, 0);
            }
            const f32x4 b2c = *(const f32x4*)&b2[nt * 16 + q * 4];
            P[nt][0] = cvt_pk_bf16(fmaxf(acc2[0] + b2c[0], 0.0f),
                                   fmaxf(acc2[1] + b2c[1], 0.0f));
            P[nt][1] = cvt_pk_bf16(fmaxf(acc2[2] + b2c[2], 0.0f),
                                   fmaxf(acc2[3] + b2c[3], 0.0f));
        }

        // ---- layer 3 TRANSPOSED: B-frag via q-group lane permutation
        f32x4 acc3[8];
        #pragma unroll
        for (int nt = 0; nt < 8; nt++) acc3[nt] = vzero;
        #pragma unroll
        for (int kb = 0; kb < 4; kb++) {
            const int r0a = __builtin_amdgcn_ds_bpermute(laA, (int)P[2 * kb][0]);
            const int r1a = __builtin_amdgcn_ds_bpermute(laA, (int)P[2 * kb][1]);
            const int r2a = __builtin_amdgcn_ds_bpermute(laB, (int)P[2 * kb][0]);
            const int r3a = __builtin_amdgcn_ds_bpermute(laB, (int)P[2 * kb][1]);
            const int r0b = __builtin_amdgcn_ds_bpermute(laA, (int)P[2 * kb + 1][0]);
            const int r1b = __builtin_amdgcn_ds_bpermute(laA, (int)P[2 * kb + 1][1]);
            const int r2b = __builtin_amdgcn_ds_bpermute(laB, (int)P[2 * kb + 1][0]);
            const int r3b = __builtin_amdgcn_ds_bpermute(laB, (int)P[2 * kb + 1][1]);
            union { unsigned int u[4]; bf16x8 v; } bf;
            bf.u[0] = (unsigned int)(selHi ? r0b : r0a);
            bf.u[1] = (unsigned int)(selHi ? r1b : r1a);
            bf.u[2] = (unsigned int)(selHi ? r2b : r2a);
            bf.u[3] = (unsigned int)(selHi ? r3b : r3a);
            #pragma unroll
            for (int nt = 0; nt < 8; nt++) {
                const bf16x8 wf = *(const bf16x8*)&W3L[((kb * 4 + q) * 128 + nt * 16 + ln16) * 8];
                acc3[nt] = __builtin_amdgcn_mfma_f32_16x16x32_bf16(wf, bf.v, acc3[nt], 0, 0, 0);
            }
        }

        // ---- epilogue. Lane holds h3[r=ln16][n = nt*16+q*4+rg] (32 vals).
        float s = 0.0f;
        #pragma unroll
        for (int nt = 0; nt < 8; nt++) {
            const f32x4 b3c = *(const f32x4*)&b3[nt * 16 + q * 4];
            #pragma unroll
            for (int rg = 0; rg < 4; rg++) {
                acc3[nt][rg] += b3c[rg];
                s += acc3[nt][rg];
            }
        }
        s += __shfl_xor(s, 16, 64);
        s += __shfl_xor(s, 32, 64);
        const float mu = s * (1.0f / 128.0f);
        float ss = 0.0f;
        #pragma unroll
        for (int nt = 0; nt < 8; nt++)
            #pragma unroll
            for (int rg = 0; rg < 4; rg++) {
                const float dv = acc3[nt][rg] - mu;
                ss += dv * dv;
            }
        ss += __shfl_xor(ss, 16, 64);
        ss += __shfl_xor(ss, 32, 64);
        const float rstd = rsqrtf(ss * (1.0f / 128.0f) + 1e-5f);
        const float msk = emask[i * 512 + j];
        float* __restrict__ orow = &out[(i * 512 + j) * 128];
        #pragma unroll
        for (int nt = 0; nt < 8; nt++) {
            const f32x4 gc = *(const f32x4*)&lng[nt * 16 + q * 4];
            const f32x4 bc = *(const f32x4*)&lnb[nt * 16 + q * 4];
            f32x4 o;
            #pragma unroll
            for (int rg = 0; rg < 4; rg++)
                o[rg] = ((acc3[nt][rg] - mu) * rstd * gc[rg] + bc[rg]) * msk;
            *(f32x4*)&orow[nt * 16 + q * 4] = o;
        }

        if (mt < 1) {
            #pragma unroll
            for (int kb = 0; kb < 4; kb++) afA[kb] = afB[kb];
        }
    }
}

// ---------------------------------------------------------------------------
extern "C" void kernel_launch(void* const* d_in, const int* in_sizes, int n_in,
                              void* d_out, int out_size, void* d_ws, size_t ws_size,
                              hipStream_t stream)
{
    const float* nf    = (const float*)d_in[0];
    const float* trans = (const float*)d_in[1];
    const float* sctr  = (const float*)d_in[2];
    const float* emask = (const float*)d_in[3];
    const float* flow  = (const float*)d_in[4];
    const float* Wn2e  = (const float*)d_in[5];
    const float* bn2e  = (const float*)d_in[6];
    const float* Wrp   = (const float*)d_in[7];
    const float* brp   = (const float*)d_in[8];
    const float* W1    = (const float*)d_in[9];
    const float* b1    = (const float*)d_in[10];
    const float* W2    = (const float*)d_in[11];
    const float* b2    = (const float*)d_in[12];
    const float* W3    = (const float*)d_in[13];
    const float* b3    = (const float*)d_in[14];
    const float* lng   = (const float*)d_in[15];
    const float* lnb   = (const float*)d_in[16];

    float* ws = (float*)d_ws;                  // needs ~1.07 MB
    float* Aw  = ws;                           // [512*128]
    float* Bv  = ws + 65536;                   // [512*128]
    float* Rm  = ws + 131072;                  // [1023*128]
    short* W2b = (short*)(ws + 262016);        // [16384] bf16, frag layout
    short* W3b = (short*)(ws + 270208);        // [16384] bf16, frag layout
    float* out = (float*)d_out;

    pre_fast<<<512, 512, 0, stream>>>(nf, flow, Wn2e, bn2e, Wrp, brp, W1, b1,
                                      W2, W3, Aw, Bv, Rm, W2b, W3b);
    edge_main<<<1024, 512, 0, stream>>>(trans, sctr, emask, W1, W2b, b2, W3b, b3,
                                        lng, lnb, Aw, Bv, Rm, out);
}

// Round 9
// 278.164 us; speedup vs baseline: 1.1334x; 1.1334x over previous
//
#include <hip/hip_runtime.h>

// ---------------------------------------------------------------------------
// EdgeFeatureNet: B=1, N=512, NODE_DIM=256, HID=128, EDGE_DIM=128, bins=22
//
// h1_pre[i,j] = A[i] + Bv[j] + R[i-j+511] + W1row[384+binD] + W1row[406+binS]
// h2 = relu(h1@W2+b2), h3 = h2@W3+b3, LayerNorm, * edge_mask.
//
// Round-9 structure:
//  - pre_fast: unchanged (verified round 5).
//  - edge_main: SAME grid (1024 blocks, 256 pairs each), but block = 1024
//    threads = 16 waves, ONE 16-row tile per wave (was 8 waves x 2 tiles).
//    Halves each wave's serial latency chain AND doubles waves/CU (32 = max)
//    as long as VGPR <= 64 — forced via __launch_bounds__(1024, 8).
//    Tile body is the round-5-verified code verbatim (transposed MFMA
//    layers 2/3, q-group bpermute remap, LN epilogue).
//  - R8's loop-carried af double-buffer (diagnosed: ~550 B/thread scratch
//    spill, +115/+285 MB FETCH/WRITE) is reverted.
// ---------------------------------------------------------------------------

using bf16x8 = __attribute__((ext_vector_type(8))) short;
using f32x4  = __attribute__((ext_vector_type(4))) float;

__device__ __forceinline__ unsigned short f2bf(float f) {
    unsigned int u;
    __builtin_memcpy(&u, &f, 4);
    unsigned int r = (u + 0x7fffu + ((u >> 16) & 1u)) >> 16;  // RNE
    return (unsigned short)r;
}

__device__ __forceinline__ unsigned int cvt_pk_bf16(float lo, float hi) {
    unsigned int r;
    asm("v_cvt_pk_bf16_f32 %0, %1, %2" : "=v"(r) : "v"(lo), "v"(hi));
    return r;
}

// ---------------------------------------------------------------------------
// pre_fast: 512 blocks x 512 threads (verified round 5, unchanged).
//   block i: A[i], Bv[i]; Rm rows {2i, 2i+1}; 64-elem W2b/W3b slice.
// ---------------------------------------------------------------------------
__global__ __launch_bounds__(512) void pre_fast(
    const float* __restrict__ nf,
    const float* __restrict__ flow,
    const float* __restrict__ Wn2e,
    const float* __restrict__ bn2e,
    const float* __restrict__ Wrp,
    const float* __restrict__ brp,
    const float* __restrict__ W1,
    const float* __restrict__ b1,
    const float* __restrict__ W2,
    const float* __restrict__ W3,
    float* __restrict__ Aw, float* __restrict__ Bv,
    float* __restrict__ Rm,
    short* __restrict__ W2b, short* __restrict__ W3b)
{
    __shared__ float nfs[256];
    __shared__ float n2s[128];
    __shared__ float red[512];
    __shared__ float emb[128];
    __shared__ float rp[128];

    const int bid = blockIdx.x;
    const int tid = threadIdx.x;
    const int i = bid;
    const int m = tid & 127, ks = tid >> 7;

    // (c) W2/W3 -> bf16 fragment layout, 64 values per block (independent)
    if (tid < 64) {
        const int idx = bid * 64 + tid;            // 0..32767
        const int v   = idx & 16383;
        const int k   = v >> 7, n = v & 127;
        const int dst = ((k >> 3) * 128 + n) * 8 + (k & 7);
        if (idx < 16384) W2b[dst] = (short)f2bf(W2[v]);
        else             W3b[dst] = (short)f2bf(W3[v]);
    }

    // (a) n2e[i] = nf[i] @ Wn2e + bn2e   (k = 0..255, 4 slices of 64)
    if (tid < 256) nfs[tid] = nf[i * 256 + tid];
    __syncthreads();
    {
        float p0 = 0.f, p1 = 0.f;
        #pragma unroll 8
        for (int k = ks * 64; k < ks * 64 + 64; k += 2) {
            p0 += nfs[k]     * Wn2e[k * 128 + m];
            p1 += nfs[k + 1] * Wn2e[(k + 1) * 128 + m];
        }
        red[tid] = p0 + p1;
    }
    __syncthreads();
    if (tid < 128)
        n2s[tid] = bn2e[tid] +
                   ((red[tid] + red[tid + 128]) + (red[tid + 256] + red[tid + 384]));
    __syncthreads();

    // A[i] = n2e@W1[0:128] + b1 + flow*W1[428];  Bv[i] = n2e@W1[128:256] + flow*W1[429]
    {
        float pa = 0.f, pb = 0.f;
        #pragma unroll 8
        for (int k = ks * 32; k < ks * 32 + 32; k++) {
            const float s = n2s[k];
            pa += s * W1[k * 128 + m];
            pb += s * W1[(128 + k) * 128 + m];
        }
        red[tid] = pa;
        __syncthreads();
        float pA = 0.f;
        if (tid < 128)
            pA = (red[tid] + red[tid + 128]) + (red[tid + 256] + red[tid + 384]);
        __syncthreads();
        red[tid] = pb;
        __syncthreads();
        if (tid < 128) {
            const float fl = flow[i];
            Aw[i * 128 + tid] = pA + b1[tid] + fl * W1[428 * 128 + tid];
            Bv[i * 128 + tid] =
                (red[tid] + red[tid + 128]) + (red[tid + 256] + red[tid + 384]) +
                fl * W1[429 * 128 + tid];
        }
    }
    __syncthreads();

    // (b) two Rm rows: dix = 2*bid, 2*bid+1 (valid 0..1022)
    for (int rr = 0; rr < 2; rr++) {
        const int dix = bid * 2 + rr;
        if (dix > 1022) break;                      // block-uniform
        const float d = (float)(dix - 511);
        if (tid < 128) {
            const int K = tid & 63;
            const float denom = powf(2056.0f, (float)K * (1.0f / 64.0f));
            const float ang = d * 3.14159265358979323846f / denom;
            emb[tid] = (tid < 64) ? sinf(ang) : cosf(ang);
        }
        __syncthreads();
        float p = 0.f;
        #pragma unroll 8
        for (int k = ks * 32; k < ks * 32 + 32; k++) p += emb[k] * Wrp[k * 128 + m];
        red[tid] = p;
        __syncthreads();
        if (tid < 128)
            rp[tid] = brp[tid] +
                      ((red[tid] + red[tid + 128]) + (red[tid + 256] + red[tid + 384]));
        __syncthreads();
        p = 0.f;
        #pragma unroll 8
        for (int k = ks * 32; k < ks * 32 + 32; k++) p += rp[k] * W1[(256 + k) * 128 + m];
        red[tid] = p;
        __syncthreads();
        if (tid < 128)
            Rm[dix * 128 + tid] =
                (red[tid] + red[tid + 128]) + (red[tid + 256] + red[tid + 384]);
        __syncthreads();
    }
}

// ---------------------------------------------------------------------------
// Main fused kernel: grid=1024 (i = bid>>1, j0 = (bid&1)*256), block=1024
// (16 waves, ONE 16-row tile per wave). LDS ~68 KB -> 2 blocks/CU (32 waves)
// if VGPR<=64 (forced). One barrier.
// ---------------------------------------------------------------------------
__global__ __launch_bounds__(1024, 8) void edge_main(
    const float* __restrict__ trans,
    const float* __restrict__ sctrans,
    const float* __restrict__ emask,
    const float* __restrict__ W1,
    const short* __restrict__ W2b,
    const float* __restrict__ b2,
    const short* __restrict__ W3b,
    const float* __restrict__ b3,
    const float* __restrict__ lng,
    const float* __restrict__ lnb,
    const float* __restrict__ A,
    const float* __restrict__ Bv,
    const float* __restrict__ Rm,
    float* __restrict__ out)
{
    __shared__ __align__(16) short W2L[16384];          // 32 KB, frag layout
    __shared__ __align__(16) short W3L[16384];          // 32 KB, frag layout
    __shared__ __align__(16) float As[128];
    __shared__ int binsD[256];
    __shared__ int binsS[256];

    const int tid = threadIdx.x;
    const int i  = blockIdx.x >> 1;
    const int j0 = (blockIdx.x & 1) << 8;

    // ---- async-stage weights into LDS: pure linear copy, 16 B/lane.
    // 1024 threads: 2 rounds cover 32 KB per buffer.
    for (int r = 0; r < 2; r++) {
        const int off = (r * 1024 + tid) * 16;          // byte offset
        __builtin_amdgcn_global_load_lds(
            (const __attribute__((address_space(1))) void*)((const char*)W2b + off),
            (__attribute__((address_space(3))) void*)((char*)W2L + off), 16, 0, 0);
        __builtin_amdgcn_global_load_lds(
            (const __attribute__((address_space(1))) void*)((const char*)W3b + off),
            (__attribute__((address_space(3))) void*)((char*)W3L + off), 16, 0, 0);
    }

    if (tid < 128) As[tid] = A[i * 128 + tid];

    // ---- per-pair distogram bins (threads 0..255: trans, 256..511: sc_trans)
    if (tid < 512) {
        const int p = tid & 255;
        const float* P = (tid < 256) ? trans : sctrans;
        const int j = j0 + p;
        const float dx = __fsub_rn(P[i * 3 + 0], P[j * 3 + 0]);
        const float dy = __fsub_rn(P[i * 3 + 1], P[j * 3 + 1]);
        const float dz = __fsub_rn(P[i * 3 + 2], P[j * 3 + 2]);
        const float d2 = __fadd_rn(__fadd_rn(__fmul_rn(dx, dx), __fmul_rn(dy, dy)),
                                   __fmul_rn(dz, dz));
        const double dd = (double)sqrtf(d2);
        const double step = (20.0 - 0.001) / 21.0;
        int bin = -1;
        for (int b = 0; b < 22; b++) {
            const double lo = (b == 21) ? 20.0 : __dadd_rn(0.001, __dmul_rn((double)b, step));
            const double up = (b == 20) ? 20.0 :
                              ((b == 21) ? 1e8 : __dadd_rn(0.001, __dmul_rn((double)(b + 1), step)));
            if (dd > lo && dd < up) bin = b;
        }
        if (tid < 256) binsD[p] = bin; else binsS[p] = bin;
    }
    __syncthreads();   // only barrier: weights staged + bins + As

    const int w = tid >> 6;       // wave id 0..15: owns pairs [16w, 16w+16)
    const int l = tid & 63;
    const int q = l >> 4;         // quad within wave
    const int ln16 = l & 15;

    const f32x4 vzero = {0.0f, 0.0f, 0.0f, 0.0f};
    // bpermute source-lane addresses for the L2->L3 q-group permutation
    const int laA = (((q & 1) * 2) * 16 + ln16) * 4;    // source quad (q&1)*2
    const int laB = laA + 64;                            // source quad (q&1)*2+1
    const bool selHi = (q >> 1) != 0;

    const int p = 16 * w + ln16;                         // local pair (row r)
    const int j = j0 + p;

    // ---- h1 directly into A-frag registers (== B-frag of h1T).
    // Lane (q,ln16), kb holds h1[row=p][f = kb*32 + q*8 + e], e=0..7.
    bf16x8 af[4];
    {
        const int didx = i - j + 511;
        const int bD = binsD[p], bS = binsS[p];
        const float sD = bD >= 0 ? 1.0f : 0.0f;
        const float sS = bS >= 0 ? 1.0f : 0.0f;
        const int rD = 384 + (bD >= 0 ? bD : 0);
        const int rS = 406 + (bS >= 0 ? bS : 0);
        const float* __restrict__ BvR = &Bv[j * 128];
        const float* __restrict__ RmR = &Rm[didx * 128];
        const float* __restrict__ WdR = &W1[rD * 128];
        const float* __restrict__ WsR = &W1[rS * 128];
        #pragma unroll
        for (int kb = 0; kb < 4; kb++) {
            const int f0 = kb * 32 + q * 8;
            const f32x4 bv0 = *(const f32x4*)&BvR[f0];
            const f32x4 bv1 = *(const f32x4*)&BvR[f0 + 4];
            const f32x4 r0  = *(const f32x4*)&RmR[f0];
            const f32x4 r1  = *(const f32x4*)&RmR[f0 + 4];
            const f32x4 a0  = *(const f32x4*)&As[f0];
            const f32x4 a1  = *(const f32x4*)&As[f0 + 4];
            const f32x4 w0  = *(const f32x4*)&WdR[f0];
            const f32x4 w1  = *(const f32x4*)&WdR[f0 + 4];
            const f32x4 s0  = *(const f32x4*)&WsR[f0];
            const f32x4 s1  = *(const f32x4*)&WsR[f0 + 4];
            float h[8];
            #pragma unroll
            for (int e = 0; e < 4; e++) {
                h[e]     = fmaxf(a0[e] + bv0[e] + r0[e] + sD * w0[e] + sS * s0[e], 0.0f);
                h[e + 4] = fmaxf(a1[e] + bv1[e] + r1[e] + sD * w1[e] + sS * s1[e], 0.0f);
            }
            union { unsigned int u[4]; bf16x8 v; } cv;
            cv.u[0] = cvt_pk_bf16(h[0], h[1]);
            cv.u[1] = cvt_pk_bf16(h[2], h[3]);
            cv.u[2] = cvt_pk_bf16(h[4], h[5]);
            cv.u[3] = cvt_pk_bf16(h[6], h[7]);
            af[kb] = cv.v;
        }
    }

    // ---- layer 2 TRANSPOSED: lane holds h2T[n = nt*16+q*4+rg][r = ln16]
    unsigned int P[8][2];
    #pragma unroll
    for (int nt = 0; nt < 8; nt++) {
        f32x4 acc2 = vzero;
        #pragma unroll
        for (int kb = 0; kb < 4; kb++) {
            const bf16x8 wf = *(const bf16x8*)&W2L[((kb * 4 + q) * 128 + nt * 16 + ln16) * 8];
            acc2 = __builtin_amdgcn_mfma_f32_16x16x32_bf16(wf, af[kb], acc2, 0, 0, 0);
        }
        const f32x4 b2c = *(const f32x4*)&b2[nt * 16 + q * 4];
        P[nt][0] = cvt_pk_bf16(fmaxf(acc2[0] + b2c[0], 0.0f),
                               fmaxf(acc2[1] + b2c[1], 0.0f));
        P[nt][1] = cvt_pk_bf16(fmaxf(acc2[2] + b2c[2], 0.0f),
                               fmaxf(acc2[3] + b2c[3], 0.0f));
    }

    // ---- layer 3 TRANSPOSED: B-frag via q-group lane permutation
    f32x4 acc3[8];
    #pragma unroll
    for (int nt = 0; nt < 8; nt++) acc3[nt] = vzero;
    #pragma unroll
    for (int kb = 0; kb < 4; kb++) {
        const int r0a = __builtin_amdgcn_ds_bpermute(laA, (int)P[2 * kb][0]);
        const int r1a = __builtin_amdgcn_ds_bpermute(laA, (int)P[2 * kb][1]);
        const int r2a = __builtin_amdgcn_ds_bpermute(laB, (int)P[2 * kb][0]);
        const int r3a = __builtin_amdgcn_ds_bpermute(laB, (int)P[2 * kb][1]);
        const int r0b = __builtin_amdgcn_ds_bpermute(laA, (int)P[2 * kb + 1][0]);
        const int r1b = __builtin_amdgcn_ds_bpermute(laA, (int)P[2 * kb + 1][1]);
        const int r2b = __builtin_amdgcn_ds_bpermute(laB, (int)P[2 * kb + 1][0]);
        const int r3b = __builtin_amdgcn_ds_bpermute(laB, (int)P[2 * kb + 1][1]);
        union { unsigned int u[4]; bf16x8 v; } bf;
        bf.u[0] = (unsigned int)(selHi ? r0b : r0a);
        bf.u[1] = (unsigned int)(selHi ? r1b : r1a);
        bf.u[2] = (unsigned int)(selHi ? r2b : r2a);
        bf.u[3] = (unsigned int)(selHi ? r3b : r3a);
        #pragma unroll
        for (int nt = 0; nt < 8; nt++) {
            const bf16x8 wf = *(const bf16x8*)&W3L[((kb * 4 + q) * 128 + nt * 16 + ln16) * 8];
            acc3[nt] = __builtin_amdgcn_mfma_f32_16x16x32_bf16(wf, bf.v, acc3[nt], 0, 0, 0);
        }
    }

    // ---- epilogue. Lane holds h3[r=ln16][n = nt*16+q*4+rg] (32 vals).
    float s = 0.0f;
    #pragma unroll
    for (int nt = 0; nt < 8; nt++) {
        const f32x4 b3c = *(const f32x4*)&b3[nt * 16 + q * 4];
        #pragma unroll
        for (int rg = 0; rg < 4; rg++) {
            acc3[nt][rg] += b3c[rg];
            s += acc3[nt][rg];
        }
    }
    s += __shfl_xor(s, 16, 64);
    s += __shfl_xor(s, 32, 64);
    const float mu = s * (1.0f / 128.0f);
    float ss = 0.0f;
    #pragma unroll
    for (int nt = 0; nt < 8; nt++)
        #pragma unroll
        for (int rg = 0; rg < 4; rg++) {
            const float dv = acc3[nt][rg] - mu;
            ss += dv * dv;
        }
    ss += __shfl_xor(ss, 16, 64);
    ss += __shfl_xor(ss, 32, 64);
    const float rstd = rsqrtf(ss * (1.0f / 128.0f) + 1e-5f);
    const float msk = emask[i * 512 + j];
    float* __restrict__ orow = &out[(i * 512 + j) * 128];
    #pragma unroll
    for (int nt = 0; nt < 8; nt++) {
        const f32x4 gc = *(const f32x4*)&lng[nt * 16 + q * 4];
        const f32x4 bc = *(const f32x4*)&lnb[nt * 16 + q * 4];
        f32x4 o;
        #pragma unroll
        for (int rg = 0; rg < 4; rg++)
            o[rg] = ((acc3[nt][rg] - mu) * rstd * gc[rg] + bc[rg]) * msk;
        *(f32x4*)&orow[nt * 16 + q * 4] = o;
    }
}

// ---------------------------------------------------------------------------
extern "C" void kernel_launch(void* const* d_in, const int* in_sizes, int n_in,
                              void* d_out, int out_size, void* d_ws, size_t ws_size,
                              hipStream_t stream)
{
    const float* nf    = (const float*)d_in[0];
    const float* trans = (const float*)d_in[1];
    const float* sctr  = (const float*)d_in[2];
    const float* emask = (const float*)d_in[3];
    const float* flow  = (const float*)d_in[4];
    const float* Wn2e  = (const float*)d_in[5];
    const float* bn2e  = (const float*)d_in[6];
    const float* Wrp   = (const float*)d_in[7];
    const float* brp   = (const float*)d_in[8];
    const float* W1    = (const float*)d_in[9];
    const float* b1    = (const float*)d_in[10];
    const float* W2    = (const float*)d_in[11];
    const float* b2    = (const float*)d_in[12];
    const float* W3    = (const float*)d_in[13];
    const float* b3    = (const float*)d_in[14];
    const float* lng   = (const float*)d_in[15];
    const float* lnb   = (const float*)d_in[16];

    float* ws = (float*)d_ws;                  // needs ~1.07 MB
    float* Aw  = ws;                           // [512*128]
    float* Bv  = ws + 65536;                   // [512*128]
    float* Rm  = ws + 131072;                  // [1023*128]
    short* W2b = (short*)(ws + 262016);        // [16384] bf16, frag layout
    short* W3b = (short*)(ws + 270208);        // [16384] bf16, frag layout
    float* out = (float*)d_out;

    pre_fast<<<512, 512, 0, stream>>>(nf, flow, Wn2e, bn2e, Wrp, brp, W1, b1,
                                      W2, W3, Aw, Bv, Rm, W2b, W3b);
    edge_main<<<1024, 1024, 0, stream>>>(trans, sctr, emask, W1, W2b, b2, W3b, b3,
                                         lng, lnb, Aw, Bv, Rm, out);
}

// Round 10
// 252.802 us; speedup vs baseline: 1.2471x; 1.1003x over previous
//
#include <hip/hip_runtime.h>

// ---------------------------------------------------------------------------
// EdgeFeatureNet: B=1, N=512, NODE_DIM=256, HID=128, EDGE_DIM=128, bins=22
//
// h1_pre[i,j] = A[i] + Bv[j] + R[i-j+511] + W1row[384+binD] + W1row[406+binS]
// h2 = relu(h1@W2+b2), h3 = h2@W3+b3, LayerNorm, * edge_mask.
//
// Round-10 = Round-9 with ONE fix: __launch_bounds__(1024, 4) instead of
// (1024, 8). R9's min-waves=8 forced a 32-VGPR cap on a ~80-VGPR body ->
// scratch spill (FETCH 20->47 MB, WRITE 151->246 MB) yet still hit 125 us
// at 65.8% occupancy. With cap 128 the same body compiled to 64 VGPR in R5,
// and 64 VGPR natively supports 8 waves/SIMD -> 2 blocks/CU stays, spill
// gone.
//
// Structure (R9): grid 1024 (i=bid>>1, j0=(bid&1)*256), block = 1024 threads
// = 16 waves, ONE 16-row tile per wave. Tile body = round-5-verified code
// (transposed MFMA layers 2/3, q-group bpermute remap, LN epilogue).
// pre_fast unchanged (verified round 5).
// ---------------------------------------------------------------------------

using bf16x8 = __attribute__((ext_vector_type(8))) short;
using f32x4  = __attribute__((ext_vector_type(4))) float;

__device__ __forceinline__ unsigned short f2bf(float f) {
    unsigned int u;
    __builtin_memcpy(&u, &f, 4);
    unsigned int r = (u + 0x7fffu + ((u >> 16) & 1u)) >> 16;  // RNE
    return (unsigned short)r;
}

__device__ __forceinline__ unsigned int cvt_pk_bf16(float lo, float hi) {
    unsigned int r;
    asm("v_cvt_pk_bf16_f32 %0, %1, %2" : "=v"(r) : "v"(lo), "v"(hi));
    return r;
}

// ---------------------------------------------------------------------------
// pre_fast: 512 blocks x 512 threads (verified round 5, unchanged).
//   block i: A[i], Bv[i]; Rm rows {2i, 2i+1}; 64-elem W2b/W3b slice.
// ---------------------------------------------------------------------------
__global__ __launch_bounds__(512) void pre_fast(
    const float* __restrict__ nf,
    const float* __restrict__ flow,
    const float* __restrict__ Wn2e,
    const float* __restrict__ bn2e,
    const float* __restrict__ Wrp,
    const float* __restrict__ brp,
    const float* __restrict__ W1,
    const float* __restrict__ b1,
    const float* __restrict__ W2,
    const float* __restrict__ W3,
    float* __restrict__ Aw, float* __restrict__ Bv,
    float* __restrict__ Rm,
    short* __restrict__ W2b, short* __restrict__ W3b)
{
    __shared__ float nfs[256];
    __shared__ float n2s[128];
    __shared__ float red[512];
    __shared__ float emb[128];
    __shared__ float rp[128];

    const int bid = blockIdx.x;
    const int tid = threadIdx.x;
    const int i = bid;
    const int m = tid & 127, ks = tid >> 7;

    // (c) W2/W3 -> bf16 fragment layout, 64 values per block (independent)
    if (tid < 64) {
        const int idx = bid * 64 + tid;            // 0..32767
        const int v   = idx & 16383;
        const int k   = v >> 7, n = v & 127;
        const int dst = ((k >> 3) * 128 + n) * 8 + (k & 7);
        if (idx < 16384) W2b[dst] = (short)f2bf(W2[v]);
        else             W3b[dst] = (short)f2bf(W3[v]);
    }

    // (a) n2e[i] = nf[i] @ Wn2e + bn2e   (k = 0..255, 4 slices of 64)
    if (tid < 256) nfs[tid] = nf[i * 256 + tid];
    __syncthreads();
    {
        float p0 = 0.f, p1 = 0.f;
        #pragma unroll 8
        for (int k = ks * 64; k < ks * 64 + 64; k += 2) {
            p0 += nfs[k]     * Wn2e[k * 128 + m];
            p1 += nfs[k + 1] * Wn2e[(k + 1) * 128 + m];
        }
        red[tid] = p0 + p1;
    }
    __syncthreads();
    if (tid < 128)
        n2s[tid] = bn2e[tid] +
                   ((red[tid] + red[tid + 128]) + (red[tid + 256] + red[tid + 384]));
    __syncthreads();

    // A[i] = n2e@W1[0:128] + b1 + flow*W1[428];  Bv[i] = n2e@W1[128:256] + flow*W1[429]
    {
        float pa = 0.f, pb = 0.f;
        #pragma unroll 8
        for (int k = ks * 32; k < ks * 32 + 32; k++) {
            const float s = n2s[k];
            pa += s * W1[k * 128 + m];
            pb += s * W1[(128 + k) * 128 + m];
        }
        red[tid] = pa;
        __syncthreads();
        float pA = 0.f;
        if (tid < 128)
            pA = (red[tid] + red[tid + 128]) + (red[tid + 256] + red[tid + 384]);
        __syncthreads();
        red[tid] = pb;
        __syncthreads();
        if (tid < 128) {
            const float fl = flow[i];
            Aw[i * 128 + tid] = pA + b1[tid] + fl * W1[428 * 128 + tid];
            Bv[i * 128 + tid] =
                (red[tid] + red[tid + 128]) + (red[tid + 256] + red[tid + 384]) +
                fl * W1[429 * 128 + tid];
        }
    }
    __syncthreads();

    // (b) two Rm rows: dix = 2*bid, 2*bid+1 (valid 0..1022)
    for (int rr = 0; rr < 2; rr++) {
        const int dix = bid * 2 + rr;
        if (dix > 1022) break;                      // block-uniform
        const float d = (float)(dix - 511);
        if (tid < 128) {
            const int K = tid & 63;
            const float denom = powf(2056.0f, (float)K * (1.0f / 64.0f));
            const float ang = d * 3.14159265358979323846f / denom;
            emb[tid] = (tid < 64) ? sinf(ang) : cosf(ang);
        }
        __syncthreads();
        float p = 0.f;
        #pragma unroll 8
        for (int k = ks * 32; k < ks * 32 + 32; k++) p += emb[k] * Wrp[k * 128 + m];
        red[tid] = p;
        __syncthreads();
        if (tid < 128)
            rp[tid] = brp[tid] +
                      ((red[tid] + red[tid + 128]) + (red[tid + 256] + red[tid + 384]));
        __syncthreads();
        p = 0.f;
        #pragma unroll 8
        for (int k = ks * 32; k < ks * 32 + 32; k++) p += rp[k] * W1[(256 + k) * 128 + m];
        red[tid] = p;
        __syncthreads();
        if (tid < 128)
            Rm[dix * 128 + tid] =
                (red[tid] + red[tid + 128]) + (red[tid + 256] + red[tid + 384]);
        __syncthreads();
    }
}

// ---------------------------------------------------------------------------
// Main fused kernel: grid=1024 (i = bid>>1, j0 = (bid&1)*256), block=1024
// (16 waves, ONE 16-row tile per wave). LDS ~68 KB; VGPR cap 128 (expect 64)
// -> 2 blocks/CU = 32 waves. One barrier.
// ---------------------------------------------------------------------------
__global__ __launch_bounds__(1024, 4) void edge_main(
    const float* __restrict__ trans,
    const float* __restrict__ sctrans,
    const float* __restrict__ emask,
    const float* __restrict__ W1,
    const short* __restrict__ W2b,
    const float* __restrict__ b2,
    const short* __restrict__ W3b,
    const float* __restrict__ b3,
    const float* __restrict__ lng,
    const float* __restrict__ lnb,
    const float* __restrict__ A,
    const float* __restrict__ Bv,
    const float* __restrict__ Rm,
    float* __restrict__ out)
{
    __shared__ __align__(16) short W2L[16384];          // 32 KB, frag layout
    __shared__ __align__(16) short W3L[16384];          // 32 KB, frag layout
    __shared__ __align__(16) float As[128];
    __shared__ int binsD[256];
    __shared__ int binsS[256];

    const int tid = threadIdx.x;
    const int i  = blockIdx.x >> 1;
    const int j0 = (blockIdx.x & 1) << 8;

    // ---- async-stage weights into LDS: pure linear copy, 16 B/lane.
    // 1024 threads: 2 rounds cover 32 KB per buffer.
    for (int r = 0; r < 2; r++) {
        const int off = (r * 1024 + tid) * 16;          // byte offset
        __builtin_amdgcn_global_load_lds(
            (const __attribute__((address_space(1))) void*)((const char*)W2b + off),
            (__attribute__((address_space(3))) void*)((char*)W2L + off), 16, 0, 0);
        __builtin_amdgcn_global_load_lds(
            (const __attribute__((address_space(1))) void*)((const char*)W3b + off),
            (__attribute__((address_space(3))) void*)((char*)W3L + off), 16, 0, 0);
    }

    if (tid < 128) As[tid] = A[i * 128 + tid];

    // ---- per-pair distogram bins (threads 0..255: trans, 256..511: sc_trans)
    if (tid < 512) {
        const int p = tid & 255;
        const float* P = (tid < 256) ? trans : sctrans;
        const int j = j0 + p;
        const float dx = __fsub_rn(P[i * 3 + 0], P[j * 3 + 0]);
        const float dy = __fsub_rn(P[i * 3 + 1], P[j * 3 + 1]);
        const float dz = __fsub_rn(P[i * 3 + 2], P[j * 3 + 2]);
        const float d2 = __fadd_rn(__fadd_rn(__fmul_rn(dx, dx), __fmul_rn(dy, dy)),
                                   __fmul_rn(dz, dz));
        const double dd = (double)sqrtf(d2);
        const double step = (20.0 - 0.001) / 21.0;
        int bin = -1;
        for (int b = 0; b < 22; b++) {
            const double lo = (b == 21) ? 20.0 : __dadd_rn(0.001, __dmul_rn((double)b, step));
            const double up = (b == 20) ? 20.0 :
                              ((b == 21) ? 1e8 : __dadd_rn(0.001, __dmul_rn((double)(b + 1), step)));
            if (dd > lo && dd < up) bin = b;
        }
        if (tid < 256) binsD[p] = bin; else binsS[p] = bin;
    }
    __syncthreads();   // only barrier: weights staged + bins + As

    const int w = tid >> 6;       // wave id 0..15: owns pairs [16w, 16w+16)
    const int l = tid & 63;
    const int q = l >> 4;         // quad within wave
    const int ln16 = l & 15;

    const f32x4 vzero = {0.0f, 0.0f, 0.0f, 0.0f};
    // bpermute source-lane addresses for the L2->L3 q-group permutation
    const int laA = (((q & 1) * 2) * 16 + ln16) * 4;    // source quad (q&1)*2
    const int laB = laA + 64;                            // source quad (q&1)*2+1
    const bool selHi = (q >> 1) != 0;

    const int p = 16 * w + ln16;                         // local pair (row r)
    const int j = j0 + p;

    // ---- h1 directly into A-frag registers (== B-frag of h1T).
    // Lane (q,ln16), kb holds h1[row=p][f = kb*32 + q*8 + e], e=0..7.
    bf16x8 af[4];
    {
        const int didx = i - j + 511;
        const int bD = binsD[p], bS = binsS[p];
        const float sD = bD >= 0 ? 1.0f : 0.0f;
        const float sS = bS >= 0 ? 1.0f : 0.0f;
        const int rD = 384 + (bD >= 0 ? bD : 0);
        const int rS = 406 + (bS >= 0 ? bS : 0);
        const float* __restrict__ BvR = &Bv[j * 128];
        const float* __restrict__ RmR = &Rm[didx * 128];
        const float* __restrict__ WdR = &W1[rD * 128];
        const float* __restrict__ WsR = &W1[rS * 128];
        #pragma unroll
        for (int kb = 0; kb < 4; kb++) {
            const int f0 = kb * 32 + q * 8;
            const f32x4 bv0 = *(const f32x4*)&BvR[f0];
            const f32x4 bv1 = *(const f32x4*)&BvR[f0 + 4];
            const f32x4 r0  = *(const f32x4*)&RmR[f0];
            const f32x4 r1  = *(const f32x4*)&RmR[f0 + 4];
            const f32x4 a0  = *(const f32x4*)&As[f0];
            const f32x4 a1  = *(const f32x4*)&As[f0 + 4];
            const f32x4 w0  = *(const f32x4*)&WdR[f0];
            const f32x4 w1  = *(const f32x4*)&WdR[f0 + 4];
            const f32x4 s0  = *(const f32x4*)&WsR[f0];
            const f32x4 s1  = *(const f32x4*)&WsR[f0 + 4];
            float h[8];
            #pragma unroll
            for (int e = 0; e < 4; e++) {
                h[e]     = fmaxf(a0[e] + bv0[e] + r0[e] + sD * w0[e] + sS * s0[e], 0.0f);
                h[e + 4] = fmaxf(a1[e] + bv1[e] + r1[e] + sD * w1[e] + sS * s1[e], 0.0f);
            }
            union { unsigned int u[4]; bf16x8 v; } cv;
            cv.u[0] = cvt_pk_bf16(h[0], h[1]);
            cv.u[1] = cvt_pk_bf16(h[2], h[3]);
            cv.u[2] = cvt_pk_bf16(h[4], h[5]);
            cv.u[3] = cvt_pk_bf16(h[6], h[7]);
            af[kb] = cv.v;
        }
    }

    // ---- layer 2 TRANSPOSED: lane holds h2T[n = nt*16+q*4+rg][r = ln16]
    unsigned int P[8][2];
    #pragma unroll
    for (int nt = 0; nt < 8; nt++) {
        f32x4 acc2 = vzero;
        #pragma unroll
        for (int kb = 0; kb < 4; kb++) {
            const bf16x8 wf = *(const bf16x8*)&W2L[((kb * 4 + q) * 128 + nt * 16 + ln16) * 8];
            acc2 = __builtin_amdgcn_mfma_f32_16x16x32_bf16(wf, af[kb], acc2, 0, 0, 0);
        }
        const f32x4 b2c = *(const f32x4*)&b2[nt * 16 + q * 4];
        P[nt][0] = cvt_pk_bf16(fmaxf(acc2[0] + b2c[0], 0.0f),
                               fmaxf(acc2[1] + b2c[1], 0.0f));
        P[nt][1] = cvt_pk_bf16(fmaxf(acc2[2] + b2c[2], 0.0f),
                               fmaxf(acc2[3] + b2c[3], 0.0f));
    }

    // ---- layer 3 TRANSPOSED: B-frag via q-group lane permutation
    f32x4 acc3[8];
    #pragma unroll
    for (int nt = 0; nt < 8; nt++) acc3[nt] = vzero;
    #pragma unroll
    for (int kb = 0; kb < 4; kb++) {
        const int r0a = __builtin_amdgcn_ds_bpermute(laA, (int)P[2 * kb][0]);
        const int r1a = __builtin_amdgcn_ds_bpermute(laA, (int)P[2 * kb][1]);
        const int r2a = __builtin_amdgcn_ds_bpermute(laB, (int)P[2 * kb][0]);
        const int r3a = __builtin_amdgcn_ds_bpermute(laB, (int)P[2 * kb][1]);
        const int r0b = __builtin_amdgcn_ds_bpermute(laA, (int)P[2 * kb + 1][0]);
        const int r1b = __builtin_amdgcn_ds_bpermute(laA, (int)P[2 * kb + 1][1]);
        const int r2b = __builtin_amdgcn_ds_bpermute(laB, (int)P[2 * kb + 1][0]);
        const int r3b = __builtin_amdgcn_ds_bpermute(laB, (int)P[2 * kb + 1][1]);
        union { unsigned int u[4]; bf16x8 v; } bf;
        bf.u[0] = (unsigned int)(selHi ? r0b : r0a);
        bf.u[1] = (unsigned int)(selHi ? r1b : r1a);
        bf.u[2] = (unsigned int)(selHi ? r2b : r2a);
        bf.u[3] = (unsigned int)(selHi ? r3b : r3a);
        #pragma unroll
        for (int nt = 0; nt < 8; nt++) {
            const bf16x8 wf = *(const bf16x8*)&W3L[((kb * 4 + q) * 128 + nt * 16 + ln16) * 8];
            acc3[nt] = __builtin_amdgcn_mfma_f32_16x16x32_bf16(wf, bf.v, acc3[nt], 0, 0, 0);
        }
    }

    // ---- epilogue. Lane holds h3[r=ln16][n = nt*16+q*4+rg] (32 vals).
    float s = 0.0f;
    #pragma unroll
    for (int nt = 0; nt < 8; nt++) {
        const f32x4 b3c = *(const f32x4*)&b3[nt * 16 + q * 4];
        #pragma unroll
        for (int rg = 0; rg < 4; rg++) {
            acc3[nt][rg] += b3c[rg];
            s += acc3[nt][rg];
        }
    }
    s += __shfl_xor(s, 16, 64);
    s += __shfl_xor(s, 32, 64);
    const float mu = s * (1.0f / 128.0f);
    float ss = 0.0f;
    #pragma unroll
    for (int nt = 0; nt < 8; nt++)
        #pragma unroll
        for (int rg = 0; rg < 4; rg++) {
            const float dv = acc3[nt][rg] - mu;
            ss += dv * dv;
        }
    ss += __shfl_xor(ss, 16, 64);
    ss += __shfl_xor(ss, 32, 64);
    const float rstd = rsqrtf(ss * (1.0f / 128.0f) + 1e-5f);
    const float msk = emask[i * 512 + j];
    float* __restrict__ orow = &out[(i * 512 + j) * 128];
    #pragma unroll
    for (int nt = 0; nt < 8; nt++) {
        const f32x4 gc = *(const f32x4*)&lng[nt * 16 + q * 4];
        const f32x4 bc = *(const f32x4*)&lnb[nt * 16 + q * 4];
        f32x4 o;
        #pragma unroll
        for (int rg = 0; rg < 4; rg++)
            o[rg] = ((acc3[nt][rg] - mu) * rstd * gc[rg] + bc[rg]) * msk;
        *(f32x4*)&orow[nt * 16 + q * 4] = o;
    }
}

// ---------------------------------------------------------------------------
extern "C" void kernel_launch(void* const* d_in, const int* in_sizes, int n_in,
                              void* d_out, int out_size, void* d_ws, size_t ws_size,
                              hipStream_t stream)
{
    const float* nf    = (const float*)d_in[0];
    const float* trans = (const float*)d_in[1];
    const float* sctr  = (const float*)d_in[2];
    const float* emask = (const float*)d_in[3];
    const float* flow  = (const float*)d_in[4];
    const float* Wn2e  = (const float*)d_in[5];
    const float* bn2e  = (const float*)d_in[6];
    const float* Wrp   = (const float*)d_in[7];
    const float* brp   = (const float*)d_in[8];
    const float* W1    = (const float*)d_in[9];
    const float* b1    = (const float*)d_in[10];
    const float* W2    = (const float*)d_in[11];
    const float* b2    = (const float*)d_in[12];
    const float* W3    = (const float*)d_in[13];
    const float* b3    = (const float*)d_in[14];
    const float* lng   = (const float*)d_in[15];
    const float* lnb   = (const float*)d_in[16];

    float* ws = (float*)d_ws;                  // needs ~1.07 MB
    float* Aw  = ws;                           // [512*128]
    float* Bv  = ws + 65536;                   // [512*128]
    float* Rm  = ws + 131072;                  // [1023*128]
    short* W2b = (short*)(ws + 262016);        // [16384] bf16, frag layout
    short* W3b = (short*)(ws + 270208);        // [16384] bf16, frag layout
    float* out = (float*)d_out;

    pre_fast<<<512, 512, 0, stream>>>(nf, flow, Wn2e, bn2e, Wrp, brp, W1, b1,
                                      W2, W3, Aw, Bv, Rm, W2b, W3b);
    edge_main<<<1024, 1024, 0, stream>>>(trans, sctr, emask, W1, W2b, b2, W3b, b3,
                                         lng, lnb, Aw, Bv, Rm, out);
}